// Round 8
// baseline (383.883 us; speedup 1.0000x reference)
//
#include <hip/hip_runtime.h>

#define E 256

typedef float f32x4 __attribute__((ext_vector_type(4)));
typedef float f32x2 __attribute__((ext_vector_type(2)));
typedef int   i32x8 __attribute__((ext_vector_type(8)));
typedef unsigned int u32;
typedef unsigned long long u64;

// ws layout (bytes):
//   [0      , 65536 )  Wx fp8 MX-A layout: [kblk(2)][lg(4)][f(256)][32B]
//   [65536  , 131072)  W2 fp8 same layout
//   [131072 , 131328)  d_fp8 (256 bytes)  d[f] = sum_i W2[i][f]*Wx[f][i]
//   [132096 , 133120)  wt  (256 f32)
//   [133120 , 134144)  b2  (256 f32)
//   [134144 , +512KB)  ht[n][f] (512 x 256 f32) = h@Wh^T + bx + bh
#define WS_W2 65536
#define WS_D  131072
#define WS_WT 132096
#define WS_B2 133120
#define WS_HT 134144

#define SCL 0x7f7f7f7f   // E8M0 127 = 2^0 in every byte

__device__ __forceinline__ u32 pack_fp8x4(float a, float b, float c, float d) {
    int v = __builtin_amdgcn_cvt_pk_fp8_f32(a, b, 0, false);
    v = __builtin_amdgcn_cvt_pk_fp8_f32(c, d, v, true);
    return (u32)v;
}
__device__ __forceinline__ u32 asu(float f) { union { float f; u32 u; } x; x.f = f; return x.u; }

// decode OCP e4m3fn byte -> f32 (LUT build only; NaN clamps to +-448)
__device__ __forceinline__ float fp8_to_f32(int b) {
    int s = (b >> 7) & 1, ex = (b >> 3) & 15, mn = b & 7;
    float v;
    if (ex == 0)            v = (float)mn * 0.001953125f;
    else if (ex == 15 && mn == 7) v = 448.f;
    else                    v = (1.f + (float)mn * 0.125f) * exp2f((float)(ex - 7));
    return s ? -v : v;
}

__global__ __launch_bounds__(256) void prep_kernel(
    const float* __restrict__ h,
    const float* __restrict__ Wx, const float* __restrict__ wx_t, const float* __restrict__ bx,
    const float* __restrict__ Wh, const float* __restrict__ wh_t, const float* __restrict__ bh,
    const float* __restrict__ W2, const float* __restrict__ b2,
    unsigned char* __restrict__ ws)
{
    __shared__ float sh[2][E];
    const int b = blockIdx.x;
    const int f = threadIdx.x;
    sh[0][f] = h[(2*b)*E + f];
    sh[1][f] = h[(2*b+1)*E + f];
    __syncthreads();

    const float* whr = Wh + f*E;
    float a0 = 0.f, a1 = 0.f;
    #pragma unroll 4
    for (int i = 0; i < E; ++i) {
        float wv = whr[i];
        a0 += wv * sh[0][i];
        a1 += wv * sh[1][i];
    }
    const float bb = bx[f] + bh[f];
    float* ht = (float*)(ws + WS_HT);
    ht[(2*b)*E + f]   = a0 + bb;
    ht[(2*b+1)*E + f] = a1 + bb;

    if (b == 0) {
        const float* wxr = Wx + f*E;
        const float* w2r = W2 + f*E;
        float accd = 0.f;
        #pragma unroll 4
        for (int i = 0; i < E; ++i) accd += W2[i*E + f] * wxr[i];
        ws[WS_D + f] = (unsigned char)(pack_fp8x4(accd, 0.f, 0.f, 0.f) & 255u);
        ((float*)(ws + WS_WT))[f] = wx_t[f] + wh_t[f];
        ((float*)(ws + WS_B2))[f] = b2[f];
        #pragma unroll
        for (int kblk = 0; kblk < 2; ++kblk) {
            #pragma unroll
            for (int lgb = 0; lgb < 4; ++lgb) {
                const int k0 = kblk*128 + lgb*32;
                const size_t off = (size_t)(((kblk*4 + lgb)*256) + f) * 32;
                u32 wq[8], w2q[8];
                #pragma unroll
                for (int j = 0; j < 8; ++j) {
                    f32x4 x = *(const f32x4*)(wxr + k0 + j*4);
                    wq[j]  = pack_fp8x4(x[0], x[1], x[2], x[3]);
                    x = *(const f32x4*)(w2r + k0 + j*4);
                    w2q[j] = pack_fp8x4(x[0], x[1], x[2], x[3]);
                }
                *(uint4*)(ws + off)            = *(uint4*)&wq[0];
                *(uint4*)(ws + off + 16)       = *(uint4*)&wq[4];
                *(uint4*)(ws + WS_W2 + off)    = *(uint4*)&w2q[0];
                *(uint4*)(ws + WS_W2 + off+16) = *(uint4*)&w2q[4];
            }
        }
    }
}

union frag { uint4 q[2]; i32x8 v; };

// One RK4 sub-eval, compile-time specialized on SUB (0..3).
template<int SUB>
__device__ __forceinline__ void eval_body(
    const frag (&awx)[8], const frag (&aw2)[8],
    unsigned char* aZ, unsigned char* aS, unsigned char* aG,
    const int (&addrB)[4], const int (&addrW)[4],
    const u32* lutb, float* hwf, const float* lb2f,
    const unsigned char* dfp8,
    f32x2 (&zb)[8], f32x2 (&sacc)[8], f32x4& ctr,
    float ht_r, float wt_r, float tnext,
    int tid, int wv, int lg, int fbase)
{
    const float dt = 0.125f;
    // ---- mm1: pre = Wx @ z + hw  (hw folded in as C-init, f32) ----
    f32x4 acc[4];
    #pragma unroll
    for (int ft = 0; ft < 4; ++ft)
        acc[ft] = *(const f32x4*)(hwf + fbase + ft*16 + lg*4);   // broadcast b128
    __builtin_amdgcn_s_setprio(1);
    #pragma unroll
    for (int kb = 0; kb < 2; ++kb) {
        frag B;
        B.q[0] = *(const uint4*)(aZ + addrB[kb*2+0]);
        B.q[1] = *(const uint4*)(aZ + addrB[kb*2+1]);
        #pragma unroll
        for (int fot = 0; fot < 4; ++fot)
            acc[fot] = __builtin_amdgcn_mfma_scale_f32_16x16x128_f8f6f4(
                awx[kb*4+fot].v, B.v, acc[fot], 0, 0, 0, SCL, 0, SCL);
    }
    __builtin_amdgcn_s_setprio(0);
    // ---- act: conflict-free LUT gather -> {sp, sg} fp8 quads -> LDS ----
    #pragma unroll
    for (int ft = 0; ft < 4; ++ft) {
        u32 q  = pack_fp8x4(acc[ft][0], acc[ft][1], acc[ft][2], acc[ft][3]);
        u32 e0 = lutb[(q & 255u) << 5];
        u32 e1 = lutb[((q >> 8) & 255u) << 5];
        u32 e2 = lutb[((q >> 16) & 255u) << 5];
        u32 e3 = lutb[(q >> 24) << 5];
        u32 t0 = __builtin_amdgcn_perm(e1, e0, 0x05040100u);   // {sp0,sg0,sp1,sg1}
        u32 t1 = __builtin_amdgcn_perm(e3, e2, 0x05040100u);
        *(u32*)(aS + addrW[ft]) = __builtin_amdgcn_perm(t1, t0, 0x06040200u); // sp quad
        *(u32*)(aG + addrW[ft]) = __builtin_amdgcn_perm(t1, t0, 0x07050301u); // sg quad
    }
    __syncthreads();                 // sp/sg visible
    // ---- mm2: k = W2 @ softplus + b2 (b2 as C-init) ----
    f32x4 acc2[4];
    #pragma unroll
    for (int ft = 0; ft < 4; ++ft)
        acc2[ft] = *(const f32x4*)(lb2f + fbase + ft*16 + lg*4);
    __builtin_amdgcn_s_setprio(1);
    #pragma unroll
    for (int kb = 0; kb < 2; ++kb) {
        frag B;
        B.q[0] = *(const uint4*)(aS + addrB[kb*2+0]);
        B.q[1] = *(const uint4*)(aS + addrB[kb*2+1]);
        #pragma unroll
        for (int fot = 0; fot < 4; ++fot)
            acc2[fot] = __builtin_amdgcn_mfma_scale_f32_16x16x128_f8f6f4(
                aw2[kb*4+fot].v, B.v, acc2[fot], 0, 0, 0, SCL, 0, SCL);
    }
    __builtin_amdgcn_s_setprio(0);
    // ---- trace MFMA (wave 0 only): ctr += d * sg, RK4 weight in B-scale ----
    if (wv == 0) {
        const u32 wescl = (SUB == 1 || SUB == 2) ? 0x80808080u : 0x7f7f7f7fu; // x2 / x1
        #pragma unroll
        for (int kb = 0; kb < 2; ++kb) {
            frag Bg, Ad;
            Bg.q[0] = *(const uint4*)(aG + addrB[kb*2+0]);
            Bg.q[1] = *(const uint4*)(aG + addrB[kb*2+1]);
            Ad.q[0] = *(const uint4*)(dfp8 + kb*128 + lg*32);      // row-replicated d
            Ad.q[1] = *(const uint4*)(dfp8 + kb*128 + lg*32 + 16);
            ctr = __builtin_amdgcn_mfma_scale_f32_16x16x128_f8f6f4(
                Ad.v, Bg.v, ctr, 0, 0, 0, SCL, 0, wescl);
        }
    }
    // ---- RK4 update (packed f32 pairs; kk = acc2, b2 already included) ----
    const f32x2 we2 = (SUB == 0 || SUB == 3) ? (f32x2){1.f,1.f} : (f32x2){2.f,2.f};
    #pragma unroll
    for (int ft = 0; ft < 4; ++ft) {
        f32x2 kl = { acc2[ft][0], acc2[ft][1] };
        f32x2 kh = { acc2[ft][2], acc2[ft][3] };
        f32x2 zl, zh;
        if (SUB == 0) { sacc[2*ft] = kl; sacc[2*ft+1] = kh; }
        else          { sacc[2*ft] += we2*kl; sacc[2*ft+1] += we2*kh; }
        if (SUB < 3) {
            const f32x2 ce2 = (SUB == 2) ? (f32x2){dt,dt} : (f32x2){0.0625f,0.0625f};
            zl = zb[2*ft]   + ce2*kl;
            zh = zb[2*ft+1] + ce2*kh;
        } else {
            const f32x2 c6 = { dt/6.f, dt/6.f };
            zb[2*ft]   += c6*sacc[2*ft];
            zb[2*ft+1] += c6*sacc[2*ft+1];
            zl = zb[2*ft]; zh = zb[2*ft+1];
        }
        *(u32*)(aZ + addrW[ft]) = pack_fp8x4(zl[0], zl[1], zh[0], zh[1]);
    }
    // ---- hw := ht + tnext*wt for the next te (te transitions only) ----
    if (SUB == 0 || SUB == 2) hwf[tid] = fmaf(tnext, wt_r, ht_r);
    __syncthreads();                 // next z (and hw) visible
}

// 4096 blocks x 256 thr; 16 samples/block; wave wv owns features [wv*64,+64).
// 2 blocks/CU co-resident, independent barriers -> cross-block pipe overlap.
__global__ __launch_bounds__(256, 2) void cnf_main(
    const float* __restrict__ hmat, const float* __restrict__ emb,
    const int* __restrict__ tgts, const unsigned char* __restrict__ ws,
    float* __restrict__ out)
{
    __shared__ __align__(16) u32 lut[256*32];             // bank-replicated {sg,sp}
    __shared__ __align__(16) unsigned char aZ[4096];      // z fp8, row-rotated
    __shared__ __align__(16) unsigned char aS[4096];      // softplus fp8
    __shared__ __align__(16) unsigned char aG[4096];      // sigmoid fp8
    __shared__ __align__(16) float hwf[E];                // ht + te*wt (f32)
    __shared__ __align__(16) float lb2f[E];
    __shared__ __align__(16) unsigned char dfp8[E];
    __shared__ float red_s[4][16];

    const int tid = threadIdx.x;
    const int bId = blockIdx.x;
    const int n   = bId >> 3;               // 8 blocks per h-row
    const int l   = tid & 63, wv = tid >> 6;
    const int lm  = l & 15,  lg = l >> 4;
    const int fbase = wv * 64;

    // ---- weight fragments -> registers ----
    frag awx[8], aw2[8];
    #pragma unroll
    for (int kblk = 0; kblk < 2; ++kblk) {
        #pragma unroll
        for (int fot = 0; fot < 4; ++fot) {
            const size_t off = (size_t)(((kblk*4 + lg)*256) + fbase + fot*16 + lm) * 32;
            awx[kblk*4+fot].q[0] = *(const uint4*)(ws + off);
            awx[kblk*4+fot].q[1] = *(const uint4*)(ws + off + 16);
            aw2[kblk*4+fot].q[0] = *(const uint4*)(ws + WS_W2 + off);
            aw2[kblk*4+fot].q[1] = *(const uint4*)(ws + WS_W2 + off + 16);
        }
    }

    // ---- per-thread params + LDS init ----
    const float ht_r = ((const float*)(ws + WS_HT))[n*E + tid];
    const float wt_r = ((const float*)(ws + WS_WT))[tid];
    hwf[tid]  = ht_r;                       // te = 0
    lb2f[tid] = ((const float*)(ws + WS_B2))[tid];
    dfp8[tid] = ws[WS_D + tid];
    {   // LUT entry for fp8 byte = tid: byte0 = sp_fp8, byte1 = sg_fp8
        float x  = fp8_to_f32(tid);
        float ax = fabsf(x);
        float em = expf(-ax);
        float sp = fmaxf(x, 0.f) + log1pf(em);
        float rr = 1.f / (1.f + em);
        float sg = (x >= 0.f) ? rr : 1.f - rr;
        u32 entry = ((pack_fp8x4(sg, 0.f, 0.f, 0.f) & 255u) << 8)
                  |  (pack_fp8x4(sp, 0.f, 0.f, 0.f) & 255u);
        #pragma unroll
        for (int bk = 0; bk < 32; ++bk) lut[tid*32 + bk] = entry;
    }
    const u32* lutb = lut + (l & 31);       // own-bank base -> conflict-free gathers

    // ---- LDS addresses: two-level row rotation rot(lm)=32(lm&7)+16(lm>>3) ----
    // b128 B-reads: bank_start = c/4 + 8(lm&7) + 4(lm>>3) -> 32 banks, 2-way (free).
    // b32 act-writes: bank = f0/4 + lg + 8(lm&7) + 4(lm>>3) -> 32 banks, 2-way (free).
    const int rot = ((lm & 7) << 5) + ((lm >> 3) << 4);
    int addrB[4], addrW[4];
    #pragma unroll
    for (int kb = 0; kb < 2; ++kb)
        #pragma unroll
        for (int hf = 0; hf < 2; ++hf)
            addrB[kb*2+hf] = lm*256 + ((kb*128 + lg*32 + hf*16 + rot) & 255);
    #pragma unroll
    for (int ft = 0; ft < 4; ++ft)
        addrW[ft] = lm*256 + ((fbase + ft*16 + lg*4 + rot) & 255);

    // ---- z0 gather, log p(z0) partial, initial z-stage ----
    const int sOwn = bId*16 + lm;
    const int tgt  = tgts[sOwn];
    const float* z0p = emb + (size_t)tgt * E;
    f32x2 zb[8], sacc[8];
    f32x4 ctr = (f32x4){0.f, 0.f, 0.f, 0.f};
    float ssq = 0.f;
    #pragma unroll
    for (int ft = 0; ft < 4; ++ft) {
        const int f0 = fbase + ft*16 + lg*4;
        f32x4 z = *(const f32x4*)(z0p + f0);
        zb[2*ft]   = (f32x2){ z[0], z[1] };
        zb[2*ft+1] = (f32x2){ z[2], z[3] };
        f32x4 hv = *(const f32x4*)(hmat + n*E + f0);
        #pragma unroll
        for (int r = 0; r < 4; ++r) { float dd = z[r] - hv[r]; ssq += dd*dd; }
        *(u32*)(aZ + addrW[ft]) = pack_fp8x4(z[0], z[1], z[2], z[3]);
    }
    ssq += __shfl_xor(ssq, 16);
    ssq += __shfl_xor(ssq, 32);
    if (l < 16) red_s[wv][lm] = ssq;
    __syncthreads();

    const float dt = 0.125f;
    #pragma unroll 1
    for (int st = 0; st < 8; ++st) {
        const float t0 = st * dt;
        eval_body<0>(awx, aw2, aZ, aS, aG, addrB, addrW, lutb, hwf, lb2f, dfp8,
                     zb, sacc, ctr, ht_r, wt_r, t0 + 0.0625f, tid, wv, lg, fbase);
        eval_body<1>(awx, aw2, aZ, aS, aG, addrB, addrW, lutb, hwf, lb2f, dfp8,
                     zb, sacc, ctr, ht_r, wt_r, 0.f, tid, wv, lg, fbase);
        eval_body<2>(awx, aw2, aZ, aS, aG, addrB, addrW, lutb, hwf, lb2f, dfp8,
                     zb, sacc, ctr, ht_r, wt_r, t0 + 0.125f, tid, wv, lg, fbase);
        eval_body<3>(awx, aw2, aZ, aS, aG, addrB, addrW, lutb, hwf, lb2f, dfp8,
                     zb, sacc, ctr, ht_r, wt_r, 0.f, tid, wv, lg, fbase);
    }

    // ---- output: wave 0 lanes 0-15 hold tr[lm] in ctr (rows replicated) ----
    if (wv == 0 && l < 16) {
        float ss = red_s[0][lm] + red_s[1][lm] + red_s[2][lm] + red_s[3][lm];
        out[sOwn] = -0.5f*ss - 235.2482645f - (dt/6.f)*ctr[0];
    }
}

extern "C" void kernel_launch(void* const* d_in, const int* in_sizes, int n_in,
                              void* d_out, int out_size, void* d_ws, size_t ws_size,
                              hipStream_t stream) {
    const float* h    = (const float*)d_in[0];
    const float* emb  = (const float*)d_in[1];
    const int*   tg   = (const int*)d_in[2];
    const float* Wx   = (const float*)d_in[3];
    const float* wx_t = (const float*)d_in[4];
    const float* bx   = (const float*)d_in[5];
    const float* Wh   = (const float*)d_in[6];
    const float* wh_t = (const float*)d_in[7];
    const float* bh   = (const float*)d_in[8];
    const float* W2   = (const float*)d_in[9];
    const float* b2   = (const float*)d_in[10];
    unsigned char* ws = (unsigned char*)d_ws;

    prep_kernel<<<dim3(256), dim3(256), 0, stream>>>(h, Wx, wx_t, bx, Wh, wh_t, bh, W2, b2, ws);
    cnf_main<<<dim3(4096), dim3(256), 0, stream>>>(h, emb, tg, ws, (float*)d_out);
}